// Round 2
// baseline (217.743 us; speedup 1.0000x reference)
//
#include <hip/hip_runtime.h>
#include <hip/hip_bf16.h>

#define EPS 1e-8f
#define B_  16
#define CIN 256
#define COUT 256
#define HW 64

typedef __bf16 bf16x8 __attribute__((ext_vector_type(8)));
typedef float  f32x4  __attribute__((ext_vector_type(4)));

__device__ __forceinline__ void async16(void* lds, const void* g) {
    __builtin_amdgcn_global_load_lds(
        (const __attribute__((address_space(1))) unsigned int*)g,
        (__attribute__((address_space(3))) unsigned int*)lds,
        16, 0, 0);
}

// ---------------- fused stats: blocks 0..255 = per-co wsq/wn_scale; block 256 = ssum ----------------
__global__ __launch_bounds__(256) void stats_kernel(const float* __restrict__ w,
                                                    const float* __restrict__ s,
                                                    float* __restrict__ wsq,
                                                    float* __restrict__ wn_scale,
                                                    float* __restrict__ ssum_out) {
    __shared__ float smem[4];
    const int t = threadIdx.x;
    const int lane = t & 63, wid = t >> 6;
    if (blockIdx.x == 256) {
        float v = 0.f;
        for (int i = t; i < B_ * CIN; i += 256) { float sv = s[i]; v += sv * sv; }
        for (int off = 32; off > 0; off >>= 1) v += __shfl_down(v, off, 64);
        if (lane == 0) smem[wid] = v;
        __syncthreads();
        if (t == 0) ssum_out[0] = smem[0] + smem[1] + smem[2] + smem[3];
        return;
    }
    const int co = blockIdx.x;
    const float* wp = w + ((size_t)co * CIN + t) * 9;
    float q = 0.f;
#pragma unroll
    for (int tp = 0; tp < 9; ++tp) { float wv = wp[tp]; q += wv * wv; }
    wsq[co * CIN + t] = q;
    float v = q;
    for (int off = 32; off > 0; off >>= 1) v += __shfl_down(v, off, 64);
    if (lane == 0) smem[wid] = v;
    __syncthreads();
    if (t == 0) wn_scale[co] = rsqrtf((smem[0] + smem[1] + smem[2] + smem[3]) / 2304.f);
}

// ---------------- fused coef + modulated-weight materialization ----------------
// wfull layout: [b][tap][cc=ci>>5][co][ci&31]  (conv A-frag = one contiguous 1 KB).
__global__ __launch_bounds__(256) void wmod_kernel(const float* __restrict__ w,
                                                   const float* __restrict__ s,
                                                   const float* __restrict__ wsq,
                                                   const float* __restrict__ wn_scale,
                                                   const float* __restrict__ ssum,
                                                   __bf16* __restrict__ wfull) {
    __shared__ float smem[4];
    __shared__ float coef_s;
    const int co = blockIdx.x;
    const int b  = blockIdx.y;
    const int ci = threadIdx.x;
    const int lane = ci & 63, wid = ci >> 6;
    const float sv = s[b * CIN + ci];
    float v = sv * sv * wsq[co * CIN + ci];
    for (int off = 32; off > 0; off >>= 1) v += __shfl_down(v, off, 64);
    if (lane == 0) smem[wid] = v;
    __syncthreads();
    if (ci == 0) {
        float S = smem[0] + smem[1] + smem[2] + smem[3];
        float sn2 = (float)(B_ * CIN) / ssum[0];
        float wn = wn_scale[co];
        coef_s = wn * sqrtf(sn2) * rsqrtf(wn * wn * sn2 * S + EPS);
    }
    __syncthreads();
    const float sc = sv * coef_s;
    const float* wp = w + ((size_t)co * CIN + ci) * 9;
    float wv[9];
#pragma unroll
    for (int tp = 0; tp < 9; ++tp) wv[tp] = wp[tp];
    const size_t obase = ((size_t)b * 9) * 65536 + (size_t)(ci >> 5) * 8192
                       + (size_t)co * 32 + (ci & 31);
#pragma unroll
    for (int tap = 0; tap < 9; ++tap)
        wfull[obase + (size_t)tap * 65536] = (__bf16)(wv[tap] * sc);
}

// ---------------- x fp32 NCHW -> bf16 [b][row][col 0..63][ci], via LDS transpose v2 ----------------
// No halo columns in xbf anymore (conv routes halo through zrow).
// LDS: dword grid [c=0..63][row of 160 dwords]; ci-pair j stored at dword c*160 + j + (j>>2).
//   write banks: (4m+i + g + const) mod 32 -> 2 lanes/bank (free)
//   read  banks: pairs 4u..4u+3 live at dwords 5u..5u+3 -> lane-stride 5 (odd) -> conflict-free
__device__ __forceinline__ uint pack2(float lo, float hi) {
    __bf16 a = (__bf16)lo, b = (__bf16)hi;
    unsigned short ua = __builtin_bit_cast(unsigned short, a);
    unsigned short ub = __builtin_bit_cast(unsigned short, b);
    return ((uint)ub << 16) | (uint)ua;
}

__global__ __launch_bounds__(256) void xbf2_kernel(const float* __restrict__ x,
                                                   __bf16* __restrict__ xbf) {
    __shared__ uint xsd[64 * 160];   // 40,960 B
    const int row = blockIdx.x;
    const int b   = blockIdx.y;
    const int t   = threadIdx.x;
    const float* xbase = x + ((size_t)b * CIN * HW + row) * HW;
#pragma unroll
    for (int k = 0; k < 8; ++k) {
        int p   = k * 256 + t;
        int ci2 = p >> 4;                 // ci pair index 0..127
        int c4  = (p & 15) * 4;           // col group
        const float* src = xbase + (size_t)(2 * ci2) * (HW * HW) + c4;
        float4 v0 = *(const float4*)src;
        float4 v1 = *(const float4*)(src + HW * HW);
        const int dj = ci2 + (ci2 >> 2);  // skewed dword slot for this pair
#pragma unroll
        for (int i = 0; i < 4; ++i)
            xsd[(c4 + i) * 160 + dj] = pack2((&v0.x)[i], (&v1.x)[i]);
    }
    __syncthreads();
    __bf16* orow = xbf + (((size_t)b * HW + row) * 64) * CIN;
#pragma unroll
    for (int k = 0; k < 8; ++k) {
        int o   = k * 256 + t;
        int col = o >> 5;                 // 0..63
        int u   = o & 31;                 // ci octet 0..31
        const uint* rp = &xsd[col * 160 + 5 * u];
        uint a0 = rp[0], a1 = rp[1], a2 = rp[2], a3 = rp[3];
        uint4 vv; vv.x = a0; vv.y = a1; vv.z = a2; vv.w = a3;
        *(uint4*)&orow[(size_t)col * CIN + u * 8] = vv;
    }
}

// ---------------- MFMA implicit-GEMM conv, v5 ----------------
// grid 1024 (XCD-affine), block 256 = 4 waves; wave wy = co quarter; one output row/block.
// v5: full software pipeline — A AND B fragments prefetched one tap ahead
// (bfn removes the per-tap lgkmcnt stall before the MFMA cluster); A also
// prefetched across the cc boundary. Double-buffered async x staging as before.
// LDS x tile (per buf): 800 slots of 16B: slot = qq*200 + irow*66 + col.
__global__ __launch_bounds__(256, 3) void conv_mfma3(const __bf16* __restrict__ xbf,
                                                     const __bf16* __restrict__ zrow,
                                                     const __bf16* __restrict__ wfull,
                                                     float* __restrict__ out) {
    __shared__ __attribute__((aligned(16))) __bf16 xs[2][800 * 8];   // 2 x 12800 B

    const int bid = blockIdx.x;
    const int b    = (bid & 7) + ((bid >= 512) ? 8 : 0);
    const int row0 = (bid >> 3) & 63;
    const int t = threadIdx.x;
    const int wy = t >> 6, lane = t & 63;
    const int m16 = lane & 15, q = lane >> 4;

    const __bf16* gsrc[4];
    unsigned ldsoff[4];
    bool val[4];
#pragma unroll
    for (int i = 0; i < 4; ++i) {
        int slot = i * 256 + t;
        val[i] = slot < 800;
        int qq  = slot / 200;
        int rem = slot - qq * 200;
        int irow = rem / 66;
        int col  = rem - irow * 66;
        int gr = row0 - 1 + irow;
        const __bf16* g;
        if (!val[i] || rem >= 198) {
            g = zrow;
        } else if ((unsigned)gr < 64u && col != 0 && col != 65) {
            g = xbf + (((size_t)b * HW + gr) * 64 + (col - 1)) * CIN + qq * 8;
        } else {
            g = zrow + col * CIN + qq * 8;    // zero halo (zrow sized past +cc*32+32 reach)
        }
        gsrc[i] = g;
        ldsoff[i] = (unsigned)slot * 16;
    }

    // prologue: stage chunk 0 into buf 0
#pragma unroll
    for (int i = 0; i < 4; ++i)
        if (val[i]) async16((char*)xs[0] + ldsoff[i], gsrc[i]);

    f32x4 acc[4][4] = {};
    const __bf16* abase = wfull + (size_t)b * 589824
                        + (size_t)(wy * 64 + m16) * 32 + q * 8;

    bf16x8 afc[4], bfc[4];
#pragma unroll
    for (int i = 0; i < 4; ++i)
        afc[i] = *(const bf16x8*)(abase + i * 512);    // cc=0, tap=0

    for (int cc = 0; cc < 8; ++cc) {
        const __bf16* wb = abase + (size_t)cc * 8192;
        __syncthreads();                       // drains chunk-cc staging
        if (cc < 7) {
#pragma unroll
            for (int i = 0; i < 4; ++i)
                if (val[i]) async16((char*)xs[(cc + 1) & 1] + ldsoff[i], gsrc[i] + cc * 32 + 32);
        }
        const __bf16* xcur = xs[cc & 1];
        {   // B tap 0 (dr=0, dc=0)
            const int rb = (q * 200 + m16) * 8;
#pragma unroll
            for (int j = 0; j < 4; ++j)
                bfc[j] = *(const bf16x8*)&xcur[rb + j * 128];
        }
#pragma unroll
        for (int tap = 0; tap < 9; ++tap) {
            bf16x8 afn[4], bfn[4];
            if (tap < 8) {
#pragma unroll
                for (int i = 0; i < 4; ++i)
                    afn[i] = *(const bf16x8*)(wb + (size_t)(tap + 1) * 65536 + i * 512);
                const int dr = (tap + 1) / 3, dc = (tap + 1) % 3;
                const int rb = (q * 200 + dr * 66 + m16 + dc) * 8;
#pragma unroll
                for (int j = 0; j < 4; ++j)
                    bfn[j] = *(const bf16x8*)&xcur[rb + j * 128];
            } else if (cc < 7) {
                // prefetch next cc's tap 0 A across the barrier
#pragma unroll
                for (int i = 0; i < 4; ++i)
                    afn[i] = *(const bf16x8*)(wb + 8192 + i * 512);
            }
            __builtin_amdgcn_s_setprio(1);
#pragma unroll
            for (int i = 0; i < 4; ++i)
#pragma unroll
                for (int j = 0; j < 4; ++j)
                    acc[i][j] = __builtin_amdgcn_mfma_f32_16x16x32_bf16(afc[i], bfc[j], acc[i][j], 0, 0, 0);
            __builtin_amdgcn_s_setprio(0);
            if (tap < 8) {
#pragma unroll
                for (int i = 0; i < 4; ++i) afc[i] = afn[i];
#pragma unroll
                for (int j = 0; j < 4; ++j) bfc[j] = bfn[j];
            } else if (cc < 7) {
#pragma unroll
                for (int i = 0; i < 4; ++i) afc[i] = afn[i];
            }
        }
    }

    // epilogue: D col = lane&15 (pixel), row = q*4+reg (co)
#pragma unroll
    for (int i = 0; i < 4; ++i) {
        const int cobase = wy * 64 + i * 16 + q * 4;
#pragma unroll
        for (int reg = 0; reg < 4; ++reg) {
            float* op = out + ((size_t)b * COUT + (cobase + reg)) * (HW * HW) + row0 * HW;
#pragma unroll
            for (int j = 0; j < 4; ++j)
                op[j * 16 + m16] = acc[i][j][reg];
        }
    }
}

extern "C" void kernel_launch(void* const* d_in, const int* in_sizes, int n_in,
                              void* d_out, int out_size, void* d_ws, size_t ws_size,
                              hipStream_t stream) {
    const float* x = (const float*)d_in[0];
    const float* s = (const float*)d_in[1];
    const float* w = (const float*)d_in[2];
    float* out = (float*)d_out;

    float* ws = (float*)d_ws;
    float*  ssum     = ws;
    float*  wn_scale = ws + 16;
    float*  wsq      = ws + 512;
    __bf16* wfull    = (__bf16*)(ws + 70656);            // 18,874,368 B
    __bf16* zrow     = (__bf16*)(ws + 4789248);          // 36,864 B zero pool (covers halo over-reach)
    __bf16* xbf      = (__bf16*)(ws + 4798464);          // 33,554,432 B (64 cols, no halo)

    hipMemsetAsync(zrow, 0, 36864, stream);
    stats_kernel<<<257, 256, 0, stream>>>(w, s, wsq, wn_scale, ssum);
    wmod_kernel<<<dim3(COUT, B_), 256, 0, stream>>>(w, s, wsq, wn_scale, ssum, wfull);
    xbf2_kernel<<<dim3(64, B_), 256, 0, stream>>>(x, xbf);
    conv_mfma3<<<1024, 256, 0, stream>>>(xbf, zrow, wfull, out);
}